// Round 6
// baseline (920.948 us; speedup 1.0000x reference)
//
#include <hip/hip_runtime.h>
#include <hip/hip_bf16.h>

// Problem constants (fixed by the reference)
#define D 128        // feature dim
#define NLAYER 3
#define NCH 4

typedef __attribute__((ext_vector_type(8))) short short8;
typedef __attribute__((ext_vector_type(4))) float f32x4;

__device__ __forceinline__ ushort f2bf(float f) {
    unsigned int u = __builtin_bit_cast(unsigned int, f);
    u += 0x7fffu + ((u >> 16) & 1u);     // RNE
    return (ushort)(u >> 16);
}
__device__ __forceinline__ float bflo(unsigned int u) {
    return __builtin_bit_cast(float, u << 16);
}
__device__ __forceinline__ float bfhi(unsigned int u) {
    return __builtin_bit_cast(float, u & 0xffff0000u);
}

// ---------------------------------------------------------------------------
// CSR construction. hist and fill are XCD-partitioned: class = bid & 7 owns
// one contiguous eighth of dst-space (random 4B atomics stay in one XCD L2).
// ---------------------------------------------------------------------------
#define FILL_CHUNK 4096
__global__ __launch_bounds__(256) void hist_part_kernel(
    const int* __restrict__ dst, int* __restrict__ deg,
    int E, int nPer, int N)
{
    int cls = blockIdx.x & 7;
    int base = (blockIdx.x >> 3) * FILL_CHUNK;
    int lo = cls * nPer;
    int hi = lo + nPer; if (hi > N) hi = N;
    int end = base + FILL_CHUNK; if (end > E) end = E;
    for (int e = base + threadIdx.x; e < end; e += 256) {
        int d = dst[e];
        if (d >= lo && d < hi) atomicAdd(&deg[d], 1);
    }
}

__global__ __launch_bounds__(256) void blocksum_kernel(
    const int* __restrict__ deg, int* __restrict__ bsum, int n)
{
    int i = blockIdx.x * 256 + threadIdx.x;
    int v = (i < n) ? deg[i] : 0;
#pragma unroll
    for (int o = 1; o < 64; o <<= 1) v += __shfl_xor(v, o);
    __shared__ int s[4];
    if ((threadIdx.x & 63) == 0) s[threadIdx.x >> 6] = v;
    __syncthreads();
    if (threadIdx.x == 0) bsum[blockIdx.x] = s[0] + s[1] + s[2] + s[3];
}

__global__ __launch_bounds__(512) void scanblk_kernel(
    const int* __restrict__ bsum, int* __restrict__ boff, int nb,
    int* __restrict__ offs, int n, int E)
{
    __shared__ int sh[512];
    int t = threadIdx.x;
    sh[t] = (t < nb) ? bsum[t] : 0;
    __syncthreads();
    for (int d = 1; d < 512; d <<= 1) {
        int v = (t >= d) ? sh[t - d] : 0;
        __syncthreads();
        sh[t] += v;
        __syncthreads();
    }
    if (t < nb) boff[t] = (t == 0) ? 0 : sh[t - 1];
    if (t == 0) offs[n] = E;
}

__global__ __launch_bounds__(256) void blockscan_kernel(
    const int* __restrict__ deg, const int* __restrict__ boff,
    int* __restrict__ offs, int* __restrict__ cursor, int n)
{
    __shared__ int sh[256];
    int t = threadIdx.x;
    int i = blockIdx.x * 256 + t;
    int v = (i < n) ? deg[i] : 0;
    sh[t] = v;
    __syncthreads();
    for (int d = 1; d < 256; d <<= 1) {
        int u = (t >= d) ? sh[t - d] : 0;
        __syncthreads();
        sh[t] += u;
        __syncthreads();
    }
    if (i < n) {
        int ex = boff[blockIdx.x] + sh[t] - v;
        offs[i] = ex; cursor[i] = ex;
    }
}

__global__ __launch_bounds__(256) void fill_part_kernel(
    const int* __restrict__ src, const int* __restrict__ dst,
    int* __restrict__ cursor, int* __restrict__ csr,
    int E, int nPer, int N)
{
    int cls = blockIdx.x & 7;
    int base = (blockIdx.x >> 3) * FILL_CHUNK;
    int lo = cls * nPer;
    int hi = lo + nPer; if (hi > N) hi = N;
    int end = base + FILL_CHUNK; if (end > E) end = E;
    for (int e = base + threadIdx.x; e < end; e += 256) {
        int d = dst[e];
        int s = src[e];
        if (d >= lo && d < hi) {
            int p = atomicAdd(&cursor[d], 1);
            csr[p] = s;
        }
    }
}

// ---------------------------------------------------------------------------
// fp32 -> bf16 bulk convert (8 elems/thread)
// ---------------------------------------------------------------------------
__global__ __launch_bounds__(256) void cvtx_kernel(
    const float* __restrict__ x, ushort* __restrict__ xb, int total8)
{
    int i = blockIdx.x * 256 + threadIdx.x;
    if (i >= total8) return;
    const float* gp = x + (size_t)i * 8;
    float4 v0 = *(const float4*)gp;
    float4 v1 = *(const float4*)(gp + 4);
    short8 pk;
    pk[0] = (short)f2bf(v0.x); pk[1] = (short)f2bf(v0.y);
    pk[2] = (short)f2bf(v0.z); pk[3] = (short)f2bf(v0.w);
    pk[4] = (short)f2bf(v1.x); pk[5] = (short)f2bf(v1.y);
    pk[6] = (short)f2bf(v1.z); pk[7] = (short)f2bf(v1.w);
    *(short8*)(xb + (size_t)i * 8) = pk;
}

// ---------------------------------------------------------------------------
// Weight transpose + fp32->bf16: Wt[c][n][k] = bf16(W[c][k][n])
// ---------------------------------------------------------------------------
__global__ void cvtW_kernel(const float* __restrict__ W, ushort* __restrict__ Wt,
                            int K, int Ncols) {
    __shared__ float tile[32][33];
    int c = blockIdx.z;
    int k0 = blockIdx.x * 32, n0 = blockIdx.y * 32;
    const float* Wc = W + (size_t)c * K * Ncols;
    ushort* Wtc = Wt + (size_t)c * K * Ncols;
    int tx = threadIdx.x & 31, ty = threadIdx.x >> 5;
#pragma unroll
    for (int i = 0; i < 4; ++i) {
        int k = k0 + ty + i * 8;
        tile[ty + i * 8][tx] = Wc[(size_t)k * Ncols + n0 + tx];
    }
    __syncthreads();
#pragma unroll
    for (int i = 0; i < 4; ++i) {
        int n = n0 + ty + i * 8;
        Wtc[(size_t)n * K + k0 + tx] = f2bf(tile[tx][ty + i * 8]);
    }
}

// ---------------------------------------------------------------------------
// Aggregation v2 (bf16 in/out, fp32 accumulate): 4 nodes per wave — each
// 16-lane quarter-wave owns one node, lane reads 16 B (8 bf16 cols) of the
// 256 B row. Per-column accumulation keeps the exact (a+b)+(c+d) unroll-4
// grouping + f2bf rounding. Do NOT fuse into the MLP kernel (R9 history:
// 32x TLP collapse, 2x regression).
// ---------------------------------------------------------------------------
__global__ __launch_bounds__(256) void agg_bf16(
    const ushort* __restrict__ h,
    const int* __restrict__ offs, const int* __restrict__ csr,
    ushort* __restrict__ outb, int n)
{
    int node = (blockIdx.x * 256 + threadIdx.x) >> 4;   // quarter-wave id
    int l16 = threadIdx.x & 15;
    if (node >= n) return;
    uint4 u = *((const uint4*)(h + (size_t)node * 128) + l16);
    float a0 = bflo(u.x), a1 = bfhi(u.x);
    float a2 = bflo(u.y), a3 = bfhi(u.y);
    float a4 = bflo(u.z), a5 = bfhi(u.z);
    float a6 = bflo(u.w), a7 = bfhi(u.w);
    int b = offs[node], e = offs[node + 1];
    int j = b;
    for (; j + 4 <= e; j += 4) {
        int s0 = csr[j], s1 = csr[j + 1], s2 = csr[j + 2], s3 = csr[j + 3];
        uint4 v0 = *((const uint4*)(h + (size_t)s0 * 128) + l16);
        uint4 v1 = *((const uint4*)(h + (size_t)s1 * 128) + l16);
        uint4 v2 = *((const uint4*)(h + (size_t)s2 * 128) + l16);
        uint4 v3 = *((const uint4*)(h + (size_t)s3 * 128) + l16);
        a0 += (bflo(v0.x) + bflo(v1.x)) + (bflo(v2.x) + bflo(v3.x));
        a1 += (bfhi(v0.x) + bfhi(v1.x)) + (bfhi(v2.x) + bfhi(v3.x));
        a2 += (bflo(v0.y) + bflo(v1.y)) + (bflo(v2.y) + bflo(v3.y));
        a3 += (bfhi(v0.y) + bfhi(v1.y)) + (bfhi(v2.y) + bfhi(v3.y));
        a4 += (bflo(v0.z) + bflo(v1.z)) + (bflo(v2.z) + bflo(v3.z));
        a5 += (bfhi(v0.z) + bfhi(v1.z)) + (bfhi(v2.z) + bfhi(v3.z));
        a6 += (bflo(v0.w) + bflo(v1.w)) + (bflo(v2.w) + bflo(v3.w));
        a7 += (bfhi(v0.w) + bfhi(v1.w)) + (bfhi(v2.w) + bfhi(v3.w));
    }
    for (; j < e; ++j) {
        uint4 v0 = *((const uint4*)(h + (size_t)csr[j] * 128) + l16);
        a0 += bflo(v0.x); a1 += bfhi(v0.x);
        a2 += bflo(v0.y); a3 += bfhi(v0.y);
        a4 += bflo(v0.z); a5 += bfhi(v0.z);
        a6 += bflo(v0.w); a7 += bfhi(v0.w);
    }
    uint4 po;
    po.x = (unsigned int)f2bf(a0) | ((unsigned int)f2bf(a1) << 16);
    po.y = (unsigned int)f2bf(a2) | ((unsigned int)f2bf(a3) << 16);
    po.z = (unsigned int)f2bf(a4) | ((unsigned int)f2bf(a5) << 16);
    po.w = (unsigned int)f2bf(a6) | ((unsigned int)f2bf(a7) << 16);
    *((uint4*)(outb + (size_t)node * 128) + l16) = po;
}

// ---------------------------------------------------------------------------
// Fused GIN-layer MLP: Out = relu(relu(relu(A@W0+b0)@W1+b1)@W2+b2)
// ---------------------------------------------------------------------------
__global__ __launch_bounds__(256) void gin_mlp_mfma(
    const ushort* __restrict__ A,
    const ushort* __restrict__ WtL,    // [3][128][128] bf16, n-major
    const float* __restrict__ biasL,   // [3][128]
    ushort* __restrict__ Out,
    int nrows)
{
    __shared__ __align__(16) ushort As[128 * 128];   // 32 KB
    __shared__ __align__(16) ushort Bs[128 * 128];   // 32 KB
    const int t = threadIdx.x;
    const int w = t >> 6, lane = t & 63;
    const int quad = lane >> 4, c15 = lane & 15;
    const int wr = w >> 1, wc = w & 1;
    const int rowbase = blockIdx.x * 128;

#pragma unroll
    for (int i = 0; i < 8; ++i) {
        int lin = (i * 4 + w) * 64 + lane;
        int row = lin >> 4, slot = lin & 15, g = slot ^ (row & 15);
        int grow = rowbase + row;
        if (grow >= nrows) grow = 0;
        const ushort* gp = A + (size_t)grow * 128 + g * 8;
        __builtin_amdgcn_global_load_lds(
            (const __attribute__((address_space(1))) void*)gp,
            (__attribute__((address_space(3))) void*)&As[(i * 4 + w) * 512],
            16, 0, 0);
    }
#pragma unroll
    for (int i = 0; i < 8; ++i) {
        int lin = (i * 4 + w) * 64 + lane;
        int n = lin >> 4, slot = lin & 15, g = slot ^ (n & 15);
        const ushort* gp = WtL + (size_t)n * 128 + g * 8;
        __builtin_amdgcn_global_load_lds(
            (const __attribute__((address_space(1))) void*)gp,
            (__attribute__((address_space(3))) void*)&Bs[(i * 4 + w) * 512],
            16, 0, 0);
    }
    __syncthreads();

    for (int s = 0; s < 3; ++s) {
        f32x4 acc[4][4];
#pragma unroll
        for (int i = 0; i < 4; ++i)
#pragma unroll
            for (int j = 0; j < 4; ++j)
#pragma unroll
                for (int r = 0; r < 4; ++r) acc[i][j][r] = 0.f;

#pragma unroll
        for (int ks = 0; ks < 4; ++ks) {
            short8 af[4], bf[4];
#pragma unroll
            for (int tr = 0; tr < 4; ++tr) {
                int r = wr * 64 + tr * 16 + c15;
                af[tr] = *(const short8*)&As[r * 128 + (((ks * 4 + quad) ^ (r & 15)) * 8)];
            }
#pragma unroll
            for (int tc = 0; tc < 4; ++tc) {
                int n = wc * 64 + tc * 16 + c15;
                bf[tc] = *(const short8*)&Bs[n * 128 + (((ks * 4 + quad) ^ (n & 15)) * 8)];
            }
#pragma unroll
            for (int tr = 0; tr < 4; ++tr)
#pragma unroll
                for (int tc = 0; tc < 4; ++tc)
                    acc[tr][tc] = __builtin_amdgcn_mfma_f32_16x16x32_bf16(
                        af[tr], bf[tc], acc[tr][tc], 0, 0, 0);
        }
        __syncthreads();

        if (s < 2) {
#pragma unroll
            for (int tc = 0; tc < 4; ++tc) {
                int col = wc * 64 + tc * 16 + c15;
                float bv = biasL[s * 128 + col];
#pragma unroll
                for (int tr = 0; tr < 4; ++tr)
#pragma unroll
                    for (int rg = 0; rg < 4; ++rg) {
                        int row = wr * 64 + tr * 16 + quad * 4 + rg;
                        As[row * 128 + (((col >> 3) ^ (row & 15)) * 8) + (col & 7)]
                            = f2bf(fmaxf(acc[tr][tc][rg] + bv, 0.f));
                    }
            }
            const ushort* Wn = WtL + (size_t)(s + 1) * 128 * 128;
#pragma unroll
            for (int i = 0; i < 8; ++i) {
                int lin = (i * 4 + w) * 64 + lane;
                int n = lin >> 4, slot = lin & 15, g = slot ^ (n & 15);
                const ushort* gp = Wn + (size_t)n * 128 + g * 8;
                __builtin_amdgcn_global_load_lds(
                    (const __attribute__((address_space(1))) void*)gp,
                    (__attribute__((address_space(3))) void*)&Bs[(i * 4 + w) * 512],
                    16, 0, 0);
            }
            __syncthreads();
        } else {
#pragma unroll
            for (int tc = 0; tc < 4; ++tc) {
                int col = wc * 64 + tc * 16 + c15;
                float bv = biasL[2 * 128 + col];
#pragma unroll
                for (int tr = 0; tr < 4; ++tr)
#pragma unroll
                    for (int rg = 0; rg < 4; ++rg) {
                        int grow = rowbase + wr * 64 + tr * 16 + quad * 4 + rg;
                        if (grow < nrows)
                            Out[(size_t)grow * 128 + col]
                                = f2bf(fmaxf(acc[tr][tc][rg] + bv, 0.f));
                    }
            }
        }
    }
}

// ---------------------------------------------------------------------------
// Fully fused channel MLP v6 (fixed compile error from R4 resubmit): B direct
// global->register (no LDS for B). R3 post-mortem: LDS pipe (16
// ds_read_b128/wave/step) as loaded as the matrix pipe, and B staging gives
// ZERO dedup (each wave owns a disjoint 64-col quadrant; Wt is n-major so a
// fragment is 16 contiguous bytes). Changes vs R3 (MFMA order/operands
// identical -> bit-identical output):
//   - B fragments loaded straight W->VGPR: ks=0 double-buffered one step
//     ahead; ks=1 issued at step top, covered by ks=0's 16 MFMAs.
//   - A stays LDS double-buffered (4-way shared), counted vmcnt(10)/(4)
//     waits only on the PREVIOUS step's A-stage + B0 loads.
//   - Phase 2: W2 fragments direct from global (L2-hot), Ts read-only ->
//     NO barriers in phase 2 (removes R8/R3's two exposed restage stalls).
//   - LDS 48 KB + launch_bounds(256,3) -> 3 blocks/CU (was 2).
// ---------------------------------------------------------------------------
__global__ __launch_bounds__(256, 3) void chan_fused_mfma(
    const ushort* __restrict__ A0, const ushort* __restrict__ A1,
    const ushort* __restrict__ A2, const ushort* __restrict__ A3,
    const ushort* __restrict__ Wt1,    // [NCH*256][512] bf16 n-major
    const float* __restrict__ b1,      // [NCH*256]
    const ushort* __restrict__ Wt2,    // [NCH][256][256] bf16 n-major
    const float* __restrict__ b2,      // [NCH*256]
    const float* __restrict__ w3,      // [NCH*256]
    const float* __restrict__ b3,      // [NCH]
    float* __restrict__ out,           // [N, NCH]
    int N, int T, int chunkT)
{
    const int bid = blockIdx.x;
    const int xcd = bid & 7;
    const int idx = bid >> 3;
    const int c = idx & 3;
    const int rt = xcd * chunkT + (idx >> 2);
    if (rt >= T) return;
    const int rowbase = rt * 64;

    __shared__ __align__(16) ushort As2[2][64 * 64];    // 16 KB (red aliases)
    __shared__ __align__(16) ushort Ts[64 * 256];       // 32 KB
    float (*red)[4] = (float (*)[4]) & As2[0][0];       // phase-3 alias, 1 KB

    const int t = threadIdx.x;
    const int w = t >> 6, lane = t & 63;
    const int quad = lane >> 4, c15 = lane & 15;
    const ushort* W1c = Wt1 + (size_t)c * 256 * 512;
    const ushort* W2c = Wt2 + (size_t)c * 256 * 256;

    // A staging geometry (R3): 512 granules = 64 rows x 8, 2 per thread
    int a_grow[2], a_g[2];
#pragma unroll
    for (int i = 0; i < 2; ++i) {
        int lin = (i * 4 + w) * 64 + lane;
        int row = lin >> 3, slot = lin & 7;
        a_g[i] = slot ^ (row & 7);
        int g = rowbase + row;
        a_grow[i] = (g < N) ? g : 0;
    }
    auto stageA = [&](int buf, int kc) {
        int ai = kc >> 7;
        const ushort* Ab = (ai == 0) ? A0 : (ai == 1) ? A1 : (ai == 2) ? A2 : A3;
        const int within = kc & 127;
#pragma unroll
        for (int i = 0; i < 2; ++i) {
            const ushort* gp = Ab + (size_t)a_grow[i] * 128 + within + a_g[i] * 8;
            __builtin_amdgcn_global_load_lds(
                (const __attribute__((address_space(1))) void*)gp,
                (__attribute__((address_space(3))) void*)&As2[buf][(i * 4 + w) * 512],
                16, 0, 0);
        }
    };

    // Per-wave B columns: n = w*64 + tc*16 + c15 (disjoint across waves)
    int ncol[4];
#pragma unroll
    for (int tc = 0; tc < 4; ++tc) ncol[tc] = w * 64 + tc * 16 + c15;

    // Direct B loads: fragment (col n, k-slice g0) = 16 contiguous bytes
    auto loadB = [&](short8 (&dst)[4], const ushort* Wn, int ldk, int kc, int ks) {
#pragma unroll
        for (int tc = 0; tc < 4; ++tc)
            dst[tc] = *(const short8*)&Wn[(size_t)ncol[tc] * ldk + kc + (ks * 4 + quad) * 8];
    };

    f32x4 acc[4][4];
#pragma unroll
    for (int i = 0; i < 4; ++i)
#pragma unroll
        for (int j = 0; j < 4; ++j)
#pragma unroll
            for (int r = 0; r < 4; ++r) acc[i][j][r] = 0.f;

    // ---- Phase 1: L1 GEMM, K = 512, 8 steps of 64, counted-vmcnt on A ----
    // stage(s)/B0(s) issued one iteration ahead; B1(s) issued at step top
    // (covered by the 16 ks=0 MFMAs). compute(s) reads As2[(s+1)&1].
    short8 bfb[2][4];                 // ks=0 fragments, double-buffered
    loadB(bfb[0], W1c, 512, 0, 0);    // B0(0): 4 loads
    stageA(1, 0);                     // A(0):  2 gload_lds
#pragma unroll
    for (int s = 0; s < 8; ++s) {
        const int cur = (s + 1) & 1;  // As2 buffer for this step
        const int bb = s & 1;         // bfb buffer for this step
        short8 bf1[4];
        loadB(bf1, W1c, 512, s * 64, 1);              // B1(s): 4 loads
        if (s < 7) {
            loadB(bfb[bb ^ 1], W1c, 512, (s + 1) * 64, 0);   // B0(s+1)
            stageA(cur ^ 1, (s + 1) * 64);                    // A(s+1)
            // outstanding newest->oldest: A(s+1)2, B0(s+1)4, B1(s)4 = 10
            // -> waits for A(s)+B0(s) (issued last iteration)
            asm volatile("s_waitcnt vmcnt(10)" ::: "memory");
        } else {
            // outstanding: B1(7)4 -> waits for A(7)+B0(7)
            asm volatile("s_waitcnt vmcnt(4)" ::: "memory");
        }
        __builtin_amdgcn_s_barrier();          // everyone's A(s) landed
        __builtin_amdgcn_sched_barrier(0);
        {   // ks = 0 (B from bfb[bb], loaded last iteration)
            short8 af[4];
#pragma unroll
            for (int tr = 0; tr < 4; ++tr) {
                int r = tr * 16 + c15;
                af[tr] = *(const short8*)&As2[cur][r * 64 + ((quad ^ (r & 7)) * 8)];
            }
#pragma unroll
            for (int tr = 0; tr < 4; ++tr)
#pragma unroll
                for (int tc = 0; tc < 4; ++tc)
                    acc[tr][tc] = __builtin_amdgcn_mfma_f32_16x16x32_bf16(
                        af[tr], bfb[bb][tc], acc[tr][tc], 0, 0, 0);
        }
        {   // ks = 1 (bf1 landed under the ks=0 MFMAs; compiler waits)
            short8 af[4];
#pragma unroll
            for (int tr = 0; tr < 4; ++tr) {
                int r = tr * 16 + c15;
                af[tr] = *(const short8*)&As2[cur][r * 64 + (((4 + quad) ^ (r & 7)) * 8)];
            }
#pragma unroll
            for (int tr = 0; tr < 4; ++tr)
#pragma unroll
                for (int tc = 0; tc < 4; ++tc)
                    acc[tr][tc] = __builtin_amdgcn_mfma_f32_16x16x32_bf16(
                        af[tr], bf1[tc], acc[tr][tc], 0, 0, 0);
        }
        __builtin_amdgcn_s_barrier();          // readers done before overwrite
    }

    // ---- T1 tile -> Ts (bf16, 32-granule XOR swizzle per row) ----
#pragma unroll
    for (int tc = 0; tc < 4; ++tc) {
        int col = ncol[tc];
        float bv = b1[c * 256 + col];
#pragma unroll
        for (int tr = 0; tr < 4; ++tr)
#pragma unroll
            for (int rg = 0; rg < 4; ++rg) {
                int row = tr * 16 + quad * 4 + rg;
                Ts[row * 256 + (((col >> 3) ^ (row & 31)) * 8) + (col & 7)]
                    = f2bf(fmaxf(acc[tr][tc][rg] + bv, 0.f));
            }
    }
    __syncthreads();                 // publish Ts (read-only afterwards)

    // ---- Phase 2: L2 GEMM, K = 256, 4 steps, NO barriers.
    //      B2 fragments direct from W2c (L2-hot); af from Ts. ----
#pragma unroll
    for (int i = 0; i < 4; ++i)
#pragma unroll
        for (int j = 0; j < 4; ++j)
#pragma unroll
            for (int r = 0; r < 4; ++r) acc[i][j][r] = 0.f;

#pragma unroll
    for (int s = 0; s < 4; ++s) {
#pragma unroll
        for (int ks = 0; ks < 2; ++ks) {
            short8 af[4], bf[4];
            const int g0 = s * 8 + ks * 4 + quad;
            loadB(bf, W2c, 256, s * 64, ks);
#pragma unroll
            for (int tr = 0; tr < 4; ++tr) {
                int r = tr * 16 + c15;
                af[tr] = *(const short8*)&Ts[r * 256 + ((g0 ^ (r & 31)) * 8)];
            }
#pragma unroll
            for (int tr = 0; tr < 4; ++tr)
#pragma unroll
                for (int tc = 0; tc < 4; ++tc)
                    acc[tr][tc] = __builtin_amdgcn_mfma_f32_16x16x32_bf16(
                        af[tr], bf[tc], acc[tr][tc], 0, 0, 0);
        }
    }

    // ---- Phase 3: relu(acc+b2) dot w3 ----
    float b2v[4], w3v[4];
#pragma unroll
    for (int tc = 0; tc < 4; ++tc) {
        int col = ncol[tc];
        b2v[tc] = b2[c * 256 + col];
        w3v[tc] = w3[c * 256 + col];
    }
    __syncthreads();                 // As2 region retired before red alias use
#pragma unroll
    for (int tr = 0; tr < 4; ++tr)
#pragma unroll
        for (int rg = 0; rg < 4; ++rg) {
            float p = 0.f;
#pragma unroll
            for (int tc = 0; tc < 4; ++tc)
                p += fmaxf(acc[tr][tc][rg] + b2v[tc], 0.f) * w3v[tc];
            p += __shfl_xor(p, 1);
            p += __shfl_xor(p, 2);
            p += __shfl_xor(p, 4);
            p += __shfl_xor(p, 8);
            if (c15 == 0) red[tr * 16 + quad * 4 + rg][w] = p;
        }
    __syncthreads();
    if (t < 64) {
        int grow = rowbase + t;
        if (grow < N) {
            float s = red[t][0] + red[t][1] + red[t][2] + red[t][3] + b3[c];
            out[(size_t)grow * NCH + c] = fmaxf(s, 0.f);
        }
    }
}

// ---------------------------------------------------------------------------
// Launch
// ---------------------------------------------------------------------------
extern "C" void kernel_launch(void* const* d_in, const int* in_sizes, int n_in,
                              void* d_out, int out_size, void* d_ws, size_t ws_size,
                              hipStream_t stream) {
    const float* x        = (const float*)d_in[0];
    const int*   eidx     = (const int*)d_in[1];
    const float* convW    = (const float*)d_in[2];
    const float* convB    = (const float*)d_in[3];
    const float* chanW1   = (const float*)d_in[4];
    const float* chanB1   = (const float*)d_in[5];
    const float* chanW2   = (const float*)d_in[6];
    const float* chanB2   = (const float*)d_in[7];
    const float* chanW3   = (const float*)d_in[8];
    const float* chanB3   = (const float*)d_in[9];
    float* out = (float*)d_out;

    const int N = in_sizes[0] / D;      // 100000
    const int E = in_sizes[1] / 2;      // 1600000
    const int* srcp = eidx;
    const int* dstp = eidx + E;
    const int nb = (N + 255) / 256;     // 391

    char* w = (char*)d_ws;
    auto take = [&](size_t bytes) {
        char* p = w;
        w += (bytes + 255) & ~(size_t)255;
        return p;
    };
    ushort* xb     = (ushort*)take((size_t)N * D * 2);
    ushort* h0     = (ushort*)take((size_t)N * D * 2);
    ushort* h1     = (ushort*)take((size_t)N * D * 2);
    ushort* h2     = (ushort*)take((size_t)N * D * 2);
    int*    deg    = (int*)take((size_t)N * 4);
    int*    offs   = (int*)take((size_t)(N + 1) * 4);
    int*    cursor = (int*)take((size_t)N * 4);
    int*    bsum   = (int*)take((size_t)nb * 4);
    int*    boff   = (int*)take((size_t)nb * 4);
    ushort* Wt1b   = (ushort*)take((size_t)NCH * 256 * 512 * 2);
    ushort* Wt2b   = (ushort*)take((size_t)NCH * 256 * 256 * 2);
    ushort* WtC    = (ushort*)take((size_t)NLAYER * 3 * D * D * 2);

    size_t used = (size_t)(w - (char*)d_ws);
    if (used > ws_size) return;
    size_t rem = ws_size - used;
    size_t need_gin = (((size_t)E * 4 + 255) & ~(size_t)255) + (size_t)N * D * 2;
    if (rem < need_gin) return;

    int*    csr = (int*)w;
    ushort* a   = (ushort*)(w + (((size_t)E * 4 + 255) & ~(size_t)255));

    // --- CSR build (XCD-partitioned hist + parallel scan + partitioned fill) ---
    hipMemsetAsync(deg, 0, (size_t)N * 4, stream);
    {
        int nchunks = (E + FILL_CHUNK - 1) / FILL_CHUNK;
        int nPer = (N + 7) / 8;
        hist_part_kernel<<<nchunks * 8, 256, 0, stream>>>(dstp, deg, E, nPer, N);
        blocksum_kernel<<<nb, 256, 0, stream>>>(deg, bsum, N);
        scanblk_kernel<<<1, 512, 0, stream>>>(bsum, boff, nb, offs, N, E);
        blockscan_kernel<<<nb, 256, 0, stream>>>(deg, boff, offs, cursor, N);
        fill_part_kernel<<<nchunks * 8, 256, 0, stream>>>(
            srcp, dstp, cursor, csr, E, nPer, N);
    }

    // --- converts (independent) ---
    cvtx_kernel<<<(N * 16 + 255) / 256, 256, 0, stream>>>(x, xb, N * 16);
    cvtW_kernel<<<dim3(512 / 32, 256 / 32, NCH), 256, 0, stream>>>(chanW1, Wt1b, 512, 256);
    cvtW_kernel<<<dim3(256 / 32, 256 / 32, NCH), 256, 0, stream>>>(chanW2, Wt2b, 256, 256);
    cvtW_kernel<<<dim3(D / 32, D / 32, NLAYER * 3), 256, 0, stream>>>(convW, WtC, D, D);

    const int rowtiles = (N + 127) / 128;
    const int aggblocks = (N * 16 + 255) / 256;      // 16 nodes per 256-thread block

    // --- GIN layers: agg + fused 3-linear MLP per layer ---
    ushort* hbuf[NLAYER] = {h0, h1, h2};
    const ushort* prev = xb;
    for (int l = 0; l < NLAYER; ++l) {
        agg_bf16<<<aggblocks, 256, 0, stream>>>(prev, offs, csr, a, N);
        gin_mlp_mfma<<<rowtiles, 256, 0, stream>>>(
            a, WtC + (size_t)l * 3 * D * D, convB + (size_t)l * 3 * D, hbuf[l], N);
        prev = hbuf[l];
    }

    // --- channel MLPs: fused, 64-row tiles, XCD-aware swizzled grid ---
    {
        const int T = (N + 63) / 64;          // 1563 row tiles
        const int chunkT = (T + 7) / 8;       // row tiles per XCD class
        const int grid = 8 * chunkT * NCH;
        chan_fused_mfma<<<grid, 256, 0, stream>>>(
            xb, h0, h1, h2,
            Wt1b, chanB1, Wt2b, chanB2, chanW3, chanB3,
            out, N, T, chunkT);
    }
}

// Round 7
// 816.291 us; speedup vs baseline: 1.1282x; 1.1282x over previous
//
#include <hip/hip_runtime.h>
#include <hip/hip_bf16.h>

// Problem constants (fixed by the reference)
#define D 128        // feature dim
#define NLAYER 3
#define NCH 4

typedef __attribute__((ext_vector_type(8))) short short8;
typedef __attribute__((ext_vector_type(4))) float f32x4;

__device__ __forceinline__ ushort f2bf(float f) {
    unsigned int u = __builtin_bit_cast(unsigned int, f);
    u += 0x7fffu + ((u >> 16) & 1u);     // RNE
    return (ushort)(u >> 16);
}
__device__ __forceinline__ float bflo(unsigned int u) {
    return __builtin_bit_cast(float, u << 16);
}
__device__ __forceinline__ float bfhi(unsigned int u) {
    return __builtin_bit_cast(float, u & 0xffff0000u);
}

// ---------------------------------------------------------------------------
// CSR construction. hist and fill are XCD-partitioned: class = bid & 7 owns
// one contiguous eighth of dst-space (random 4B atomics stay in one XCD L2).
// ---------------------------------------------------------------------------
#define FILL_CHUNK 4096
__global__ __launch_bounds__(256) void hist_part_kernel(
    const int* __restrict__ dst, int* __restrict__ deg,
    int E, int nPer, int N)
{
    int cls = blockIdx.x & 7;
    int base = (blockIdx.x >> 3) * FILL_CHUNK;
    int lo = cls * nPer;
    int hi = lo + nPer; if (hi > N) hi = N;
    int end = base + FILL_CHUNK; if (end > E) end = E;
    for (int e = base + threadIdx.x; e < end; e += 256) {
        int d = dst[e];
        if (d >= lo && d < hi) atomicAdd(&deg[d], 1);
    }
}

__global__ __launch_bounds__(256) void blocksum_kernel(
    const int* __restrict__ deg, int* __restrict__ bsum, int n)
{
    int i = blockIdx.x * 256 + threadIdx.x;
    int v = (i < n) ? deg[i] : 0;
#pragma unroll
    for (int o = 1; o < 64; o <<= 1) v += __shfl_xor(v, o);
    __shared__ int s[4];
    if ((threadIdx.x & 63) == 0) s[threadIdx.x >> 6] = v;
    __syncthreads();
    if (threadIdx.x == 0) bsum[blockIdx.x] = s[0] + s[1] + s[2] + s[3];
}

__global__ __launch_bounds__(512) void scanblk_kernel(
    const int* __restrict__ bsum, int* __restrict__ boff, int nb,
    int* __restrict__ offs, int n, int E)
{
    __shared__ int sh[512];
    int t = threadIdx.x;
    sh[t] = (t < nb) ? bsum[t] : 0;
    __syncthreads();
    for (int d = 1; d < 512; d <<= 1) {
        int v = (t >= d) ? sh[t - d] : 0;
        __syncthreads();
        sh[t] += v;
        __syncthreads();
    }
    if (t < nb) boff[t] = (t == 0) ? 0 : sh[t - 1];
    if (t == 0) offs[n] = E;
}

__global__ __launch_bounds__(256) void blockscan_kernel(
    const int* __restrict__ deg, const int* __restrict__ boff,
    int* __restrict__ offs, int* __restrict__ cursor, int n)
{
    __shared__ int sh[256];
    int t = threadIdx.x;
    int i = blockIdx.x * 256 + t;
    int v = (i < n) ? deg[i] : 0;
    sh[t] = v;
    __syncthreads();
    for (int d = 1; d < 256; d <<= 1) {
        int u = (t >= d) ? sh[t - d] : 0;
        __syncthreads();
        sh[t] += u;
        __syncthreads();
    }
    if (i < n) {
        int ex = boff[blockIdx.x] + sh[t] - v;
        offs[i] = ex; cursor[i] = ex;
    }
}

__global__ __launch_bounds__(256) void fill_part_kernel(
    const int* __restrict__ src, const int* __restrict__ dst,
    int* __restrict__ cursor, int* __restrict__ csr,
    int E, int nPer, int N)
{
    int cls = blockIdx.x & 7;
    int base = (blockIdx.x >> 3) * FILL_CHUNK;
    int lo = cls * nPer;
    int hi = lo + nPer; if (hi > N) hi = N;
    int end = base + FILL_CHUNK; if (end > E) end = E;
    for (int e = base + threadIdx.x; e < end; e += 256) {
        int d = dst[e];
        int s = src[e];
        if (d >= lo && d < hi) {
            int p = atomicAdd(&cursor[d], 1);
            csr[p] = s;
        }
    }
}

// ---------------------------------------------------------------------------
// fp32 -> bf16 bulk convert (8 elems/thread)
// ---------------------------------------------------------------------------
__global__ __launch_bounds__(256) void cvtx_kernel(
    const float* __restrict__ x, ushort* __restrict__ xb, int total8)
{
    int i = blockIdx.x * 256 + threadIdx.x;
    if (i >= total8) return;
    const float* gp = x + (size_t)i * 8;
    float4 v0 = *(const float4*)gp;
    float4 v1 = *(const float4*)(gp + 4);
    short8 pk;
    pk[0] = (short)f2bf(v0.x); pk[1] = (short)f2bf(v0.y);
    pk[2] = (short)f2bf(v0.z); pk[3] = (short)f2bf(v0.w);
    pk[4] = (short)f2bf(v1.x); pk[5] = (short)f2bf(v1.y);
    pk[6] = (short)f2bf(v1.z); pk[7] = (short)f2bf(v1.w);
    *(short8*)(xb + (size_t)i * 8) = pk;
}

// ---------------------------------------------------------------------------
// Weight transpose + fp32->bf16: Wt[c][n][k] = bf16(W[c][k][n])
// ---------------------------------------------------------------------------
__global__ void cvtW_kernel(const float* __restrict__ W, ushort* __restrict__ Wt,
                            int K, int Ncols) {
    __shared__ float tile[32][33];
    int c = blockIdx.z;
    int k0 = blockIdx.x * 32, n0 = blockIdx.y * 32;
    const float* Wc = W + (size_t)c * K * Ncols;
    ushort* Wtc = Wt + (size_t)c * K * Ncols;
    int tx = threadIdx.x & 31, ty = threadIdx.x >> 5;
#pragma unroll
    for (int i = 0; i < 4; ++i) {
        int k = k0 + ty + i * 8;
        tile[ty + i * 8][tx] = Wc[(size_t)k * Ncols + n0 + tx];
    }
    __syncthreads();
#pragma unroll
    for (int i = 0; i < 4; ++i) {
        int n = n0 + ty + i * 8;
        Wtc[(size_t)n * K + k0 + tx] = f2bf(tile[tx][ty + i * 8]);
    }
}

// ---------------------------------------------------------------------------
// Aggregation v3: v2 + 2-stage software pipeline. The per-group serial chain
// (csr idx load -> 4 row gathers -> accumulate) is decoupled: indices are
// prefetched one group ahead of their gathers, gathers one group ahead of
// their accumulate (~8 rows in flight per quarter-wave vs 4). Group order
// and the (a+b)+(c+d) pairing are IDENTICAL to v2 -> bit-identical output.
// Do NOT fuse into the MLP kernel (R9 history: 32x TLP collapse).
// ---------------------------------------------------------------------------
__global__ __launch_bounds__(256) void agg_bf16(
    const ushort* __restrict__ h,
    const int* __restrict__ offs, const int* __restrict__ csr,
    ushort* __restrict__ outb, int n)
{
    int node = (blockIdx.x * 256 + threadIdx.x) >> 4;   // quarter-wave id
    int l16 = threadIdx.x & 15;
    if (node >= n) return;
    uint4 u = *((const uint4*)(h + (size_t)node * 128) + l16);
    float a0 = bflo(u.x), a1 = bfhi(u.x);
    float a2 = bflo(u.y), a3 = bfhi(u.y);
    float a4 = bflo(u.z), a5 = bfhi(u.z);
    float a6 = bflo(u.w), a7 = bfhi(u.w);
    int b = offs[node], e = offs[node + 1];
    int j = b;

#define ACC4(v0, v1, v2, v3)                                         \
    do {                                                             \
        a0 += (bflo(v0.x) + bflo(v1.x)) + (bflo(v2.x) + bflo(v3.x)); \
        a1 += (bfhi(v0.x) + bfhi(v1.x)) + (bfhi(v2.x) + bfhi(v3.x)); \
        a2 += (bflo(v0.y) + bflo(v1.y)) + (bflo(v2.y) + bflo(v3.y)); \
        a3 += (bfhi(v0.y) + bfhi(v1.y)) + (bfhi(v2.y) + bfhi(v3.y)); \
        a4 += (bflo(v0.z) + bflo(v1.z)) + (bflo(v2.z) + bflo(v3.z)); \
        a5 += (bfhi(v0.z) + bfhi(v1.z)) + (bfhi(v2.z) + bfhi(v3.z)); \
        a6 += (bflo(v0.w) + bflo(v1.w)) + (bflo(v2.w) + bflo(v3.w)); \
        a7 += (bfhi(v0.w) + bfhi(v1.w)) + (bfhi(v2.w) + bfhi(v3.w)); \
    } while (0)

    if (j + 4 <= e) {
        // group 0 indices + gathers
        int i0 = csr[j], i1 = csr[j + 1], i2 = csr[j + 2], i3 = csr[j + 3];
        uint4 v0 = *((const uint4*)(h + (size_t)i0 * 128) + l16);
        uint4 v1 = *((const uint4*)(h + (size_t)i1 * 128) + l16);
        uint4 v2 = *((const uint4*)(h + (size_t)i2 * 128) + l16);
        uint4 v3 = *((const uint4*)(h + (size_t)i3 * 128) + l16);
        j += 4;
        // group 1 indices (prefetched)
        int p0 = 0, p1 = 0, p2 = 0, p3 = 0;
        bool have = (j + 4 <= e);
        if (have) { p0 = csr[j]; p1 = csr[j + 1]; p2 = csr[j + 2]; p3 = csr[j + 3]; }
        while (have) {
            // issue group k+1 gathers (indices loaded last iteration)
            uint4 w0 = *((const uint4*)(h + (size_t)p0 * 128) + l16);
            uint4 w1 = *((const uint4*)(h + (size_t)p1 * 128) + l16);
            uint4 w2 = *((const uint4*)(h + (size_t)p2 * 128) + l16);
            uint4 w3 = *((const uint4*)(h + (size_t)p3 * 128) + l16);
            // prefetch group k+2 indices
            int nj = j + 4;
            bool nxt = (nj + 4 <= e);
            if (nxt) { p0 = csr[nj]; p1 = csr[nj + 1]; p2 = csr[nj + 2]; p3 = csr[nj + 3]; }
            // accumulate group k (its gathers have had a full iteration to land)
            ACC4(v0, v1, v2, v3);
            v0 = w0; v1 = w1; v2 = w2; v3 = w3;
            j = nj; have = nxt;
        }
        ACC4(v0, v1, v2, v3);       // final full group
    }
    for (; j < e; ++j) {
        uint4 v0 = *((const uint4*)(h + (size_t)csr[j] * 128) + l16);
        a0 += bflo(v0.x); a1 += bfhi(v0.x);
        a2 += bflo(v0.y); a3 += bfhi(v0.y);
        a4 += bflo(v0.z); a5 += bfhi(v0.z);
        a6 += bflo(v0.w); a7 += bfhi(v0.w);
    }
#undef ACC4
    uint4 po;
    po.x = (unsigned int)f2bf(a0) | ((unsigned int)f2bf(a1) << 16);
    po.y = (unsigned int)f2bf(a2) | ((unsigned int)f2bf(a3) << 16);
    po.z = (unsigned int)f2bf(a4) | ((unsigned int)f2bf(a5) << 16);
    po.w = (unsigned int)f2bf(a6) | ((unsigned int)f2bf(a7) << 16);
    *((uint4*)(outb + (size_t)node * 128) + l16) = po;
}

// ---------------------------------------------------------------------------
// Fused GIN-layer MLP: Out = relu(relu(relu(A@W0+b0)@W1+b1)@W2+b2)
// ---------------------------------------------------------------------------
__global__ __launch_bounds__(256) void gin_mlp_mfma(
    const ushort* __restrict__ A,
    const ushort* __restrict__ WtL,    // [3][128][128] bf16, n-major
    const float* __restrict__ biasL,   // [3][128]
    ushort* __restrict__ Out,
    int nrows)
{
    __shared__ __align__(16) ushort As[128 * 128];   // 32 KB
    __shared__ __align__(16) ushort Bs[128 * 128];   // 32 KB
    const int t = threadIdx.x;
    const int w = t >> 6, lane = t & 63;
    const int quad = lane >> 4, c15 = lane & 15;
    const int wr = w >> 1, wc = w & 1;
    const int rowbase = blockIdx.x * 128;

#pragma unroll
    for (int i = 0; i < 8; ++i) {
        int lin = (i * 4 + w) * 64 + lane;
        int row = lin >> 4, slot = lin & 15, g = slot ^ (row & 15);
        int grow = rowbase + row;
        if (grow >= nrows) grow = 0;
        const ushort* gp = A + (size_t)grow * 128 + g * 8;
        __builtin_amdgcn_global_load_lds(
            (const __attribute__((address_space(1))) void*)gp,
            (__attribute__((address_space(3))) void*)&As[(i * 4 + w) * 512],
            16, 0, 0);
    }
#pragma unroll
    for (int i = 0; i < 8; ++i) {
        int lin = (i * 4 + w) * 64 + lane;
        int n = lin >> 4, slot = lin & 15, g = slot ^ (n & 15);
        const ushort* gp = WtL + (size_t)n * 128 + g * 8;
        __builtin_amdgcn_global_load_lds(
            (const __attribute__((address_space(1))) void*)gp,
            (__attribute__((address_space(3))) void*)&Bs[(i * 4 + w) * 512],
            16, 0, 0);
    }
    __syncthreads();

    for (int s = 0; s < 3; ++s) {
        f32x4 acc[4][4];
#pragma unroll
        for (int i = 0; i < 4; ++i)
#pragma unroll
            for (int j = 0; j < 4; ++j)
#pragma unroll
                for (int r = 0; r < 4; ++r) acc[i][j][r] = 0.f;

#pragma unroll
        for (int ks = 0; ks < 4; ++ks) {
            short8 af[4], bf[4];
#pragma unroll
            for (int tr = 0; tr < 4; ++tr) {
                int r = wr * 64 + tr * 16 + c15;
                af[tr] = *(const short8*)&As[r * 128 + (((ks * 4 + quad) ^ (r & 15)) * 8)];
            }
#pragma unroll
            for (int tc = 0; tc < 4; ++tc) {
                int n = wc * 64 + tc * 16 + c15;
                bf[tc] = *(const short8*)&Bs[n * 128 + (((ks * 4 + quad) ^ (n & 15)) * 8)];
            }
#pragma unroll
            for (int tr = 0; tr < 4; ++tr)
#pragma unroll
                for (int tc = 0; tc < 4; ++tc)
                    acc[tr][tc] = __builtin_amdgcn_mfma_f32_16x16x32_bf16(
                        af[tr], bf[tc], acc[tr][tc], 0, 0, 0);
        }
        __syncthreads();

        if (s < 2) {
#pragma unroll
            for (int tc = 0; tc < 4; ++tc) {
                int col = wc * 64 + tc * 16 + c15;
                float bv = biasL[s * 128 + col];
#pragma unroll
                for (int tr = 0; tr < 4; ++tr)
#pragma unroll
                    for (int rg = 0; rg < 4; ++rg) {
                        int row = wr * 64 + tr * 16 + quad * 4 + rg;
                        As[row * 128 + (((col >> 3) ^ (row & 15)) * 8) + (col & 7)]
                            = f2bf(fmaxf(acc[tr][tc][rg] + bv, 0.f));
                    }
            }
            const ushort* Wn = WtL + (size_t)(s + 1) * 128 * 128;
#pragma unroll
            for (int i = 0; i < 8; ++i) {
                int lin = (i * 4 + w) * 64 + lane;
                int n = lin >> 4, slot = lin & 15, g = slot ^ (n & 15);
                const ushort* gp = Wn + (size_t)n * 128 + g * 8;
                __builtin_amdgcn_global_load_lds(
                    (const __attribute__((address_space(1))) void*)gp,
                    (__attribute__((address_space(3))) void*)&Bs[(i * 4 + w) * 512],
                    16, 0, 0);
            }
            __syncthreads();
        } else {
#pragma unroll
            for (int tc = 0; tc < 4; ++tc) {
                int col = wc * 64 + tc * 16 + c15;
                float bv = biasL[2 * 128 + col];
#pragma unroll
                for (int tr = 0; tr < 4; ++tr)
#pragma unroll
                    for (int rg = 0; rg < 4; ++rg) {
                        int grow = rowbase + wr * 64 + tr * 16 + quad * 4 + rg;
                        if (grow < nrows)
                            Out[(size_t)grow * 128 + col]
                                = f2bf(fmaxf(acc[tr][tc][rg] + bv, 0.f));
                    }
            }
        }
    }
}

// ---------------------------------------------------------------------------
// Fully fused channel MLP (R3-exact revert — best measured: 233.9 us).
// R8 geometry + counted-vmcnt pipeline (T4). Per phase-1 step s:
//    issue stage(s+1); s_waitcnt vmcnt(10) (waits only stage(s), issued a
//    full iteration earlier); s_barrier; ds_read + 32 MFMA; s_barrier.
// LDS 80 KB (2 blocks/CU): As2 2x8K (red aliases), Bs2 2x32K, Ts = Bs2[1].
// Phase 2 = R8-exact. v6 post-mortem: direct-B + launch_bounds(256,3)
// spilled (VGPR 84, WRITE_SIZE 39 MB/dispatch) -> reverted.
// ---------------------------------------------------------------------------
__global__ __launch_bounds__(256, 2) void chan_fused_mfma(
    const ushort* __restrict__ A0, const ushort* __restrict__ A1,
    const ushort* __restrict__ A2, const ushort* __restrict__ A3,
    const ushort* __restrict__ Wt1,    // [NCH*256][512] bf16 n-major
    const float* __restrict__ b1,      // [NCH*256]
    const ushort* __restrict__ Wt2,    // [NCH][256][256] bf16 n-major
    const float* __restrict__ b2,      // [NCH*256]
    const float* __restrict__ w3,      // [NCH*256]
    const float* __restrict__ b3,      // [NCH]
    float* __restrict__ out,           // [N, NCH]
    int N, int T, int chunkT)
{
    const int bid = blockIdx.x;
    const int xcd = bid & 7;
    const int idx = bid >> 3;
    const int c = idx & 3;
    const int rt = xcd * chunkT + (idx >> 2);
    if (rt >= T) return;
    const int rowbase = rt * 64;

    __shared__ __align__(16) ushort As2[2][64 * 64];    // 16 KB (red aliases)
    __shared__ __align__(16) ushort Bs2[2][256 * 64];   // 64 KB (Ts = Bs2[1])
    ushort* Ts = &Bs2[1][0];
    float (*red)[4] = (float (*)[4]) & As2[0][0];       // phase-3 alias, 1 KB

    const int t = threadIdx.x;
    const int w = t >> 6, lane = t & 63;
    const int quad = lane >> 4, c15 = lane & 15;
    const ushort* W1c = Wt1 + (size_t)c * 256 * 512;
    const ushort* W2c = Wt2 + (size_t)c * 256 * 256;

    // A staging geometry (R8): 512 granules = 64 rows x 8, 2 per thread
    int a_grow[2], a_g[2];
#pragma unroll
    for (int i = 0; i < 2; ++i) {
        int lin = (i * 4 + w) * 64 + lane;
        int row = lin >> 3, slot = lin & 7;
        a_g[i] = slot ^ (row & 7);
        int g = rowbase + row;
        a_grow[i] = (g < N) ? g : 0;
    }
    auto stageA = [&](int buf, int kc) {
        int ai = kc >> 7;
        const ushort* Ab = (ai == 0) ? A0 : (ai == 1) ? A1 : (ai == 2) ? A2 : A3;
        const int within = kc & 127;
#pragma unroll
        for (int i = 0; i < 2; ++i) {
            const ushort* gp = Ab + (size_t)a_grow[i] * 128 + within + a_g[i] * 8;
            __builtin_amdgcn_global_load_lds(
                (const __attribute__((address_space(1))) void*)gp,
                (__attribute__((address_space(3))) void*)&As2[buf][(i * 4 + w) * 512],
                16, 0, 0);
        }
    };
    // B staging geometry (R8): 2048 granules = 256 n-rows x 8, 8 per thread
    int b_n[8], b_g[8];
#pragma unroll
    for (int i = 0; i < 8; ++i) {
        int lin = (i * 4 + w) * 64 + lane;
        b_n[i] = lin >> 3;
        b_g[i] = (lin & 7) ^ (b_n[i] & 7);
    }
    auto stageB = [&](int buf, const ushort* Wn, int ldk, int kc) {
#pragma unroll
        for (int i = 0; i < 8; ++i) {
            const ushort* gp = Wn + (size_t)b_n[i] * ldk + kc + b_g[i] * 8;
            __builtin_amdgcn_global_load_lds(
                (const __attribute__((address_space(1))) void*)gp,
                (__attribute__((address_space(3))) void*)&Bs2[buf][(i * 4 + w) * 512],
                16, 0, 0);
        }
    };

    f32x4 acc[4][4];
#pragma unroll
    for (int i = 0; i < 4; ++i)
#pragma unroll
        for (int j = 0; j < 4; ++j)
#pragma unroll
            for (int r = 0; r < 4; ++r) acc[i][j][r] = 0.f;

    // ---- Phase 1: L1 GEMM, K = 512, 8 counted-vmcnt steps of 64 ----
    // stage(s) lands in buf[(s+1)&1]; compute(s) reads buf[(s+1)&1].
    stageA(1, 0);
    stageB(1, W1c, 512, 0);          // stage(0) -> buf1; 10 loads in flight
#pragma unroll
    for (int s = 0; s < 8; ++s) {
        const int cur = (s + 1) & 1;
        if (s < 7) {                 // stage(s+1) -> buf[cur^1]
            stageA(cur ^ 1, (s + 1) * 64);
            stageB(cur ^ 1, W1c, 512, (s + 1) * 64);
            asm volatile("s_waitcnt vmcnt(10)" ::: "memory");  // stage(s) done
        } else {
            asm volatile("s_waitcnt vmcnt(0)" ::: "memory");   // issued 1 iter ago
        }
        __builtin_amdgcn_s_barrier();          // everyone's stage(s) landed
        __builtin_amdgcn_sched_barrier(0);
#pragma unroll
        for (int ks = 0; ks < 2; ++ks) {
            short8 af[4], bf[4];
#pragma unroll
            for (int tr = 0; tr < 4; ++tr) {
                int r = tr * 16 + c15;
                af[tr] = *(const short8*)&As2[cur][r * 64 + (((ks * 4 + quad) ^ (r & 7)) * 8)];
            }
#pragma unroll
            for (int tc = 0; tc < 4; ++tc) {
                int n = w * 64 + tc * 16 + c15;
                bf[tc] = *(const short8*)&Bs2[cur][n * 64 + (((ks * 4 + quad) ^ (n & 7)) * 8)];
            }
#pragma unroll
            for (int tr = 0; tr < 4; ++tr)
#pragma unroll
                for (int tc = 0; tc < 4; ++tc)
                    acc[tr][tc] = __builtin_amdgcn_mfma_f32_16x16x32_bf16(
                        af[tr], bf[tc], acc[tr][tc], 0, 0, 0);
        }
        __builtin_amdgcn_s_barrier();          // readers done before overwrite
    }

    // ---- Ts (= Bs2[1], free: step 7 computed from buf0) + W2 step-0 cover ----
    stageB(0, W2c, 256, 0);          // covered by the Ts write below
#pragma unroll
    for (int tc = 0; tc < 4; ++tc) {
        int col = w * 64 + tc * 16 + c15;
        float bv = b1[c * 256 + col];
#pragma unroll
        for (int tr = 0; tr < 4; ++tr)
#pragma unroll
            for (int rg = 0; rg < 4; ++rg) {
                int row = tr * 16 + quad * 4 + rg;
                Ts[row * 256 + (((col >> 3) ^ (row & 31)) * 8) + (col & 7)]
                    = f2bf(fmaxf(acc[tr][tc][rg] + bv, 0.f));
            }
    }
    __syncthreads();                 // drains W2(0) + publishes Ts

    // ---- Phase 2: L2 GEMM, K = 256, 4 steps, W2 single-buffered (R8) ----
#pragma unroll
    for (int i = 0; i < 4; ++i)
#pragma unroll
        for (int j = 0; j < 4; ++j)
#pragma unroll
            for (int r = 0; r < 4; ++r) acc[i][j][r] = 0.f;

#pragma unroll
    for (int s = 0; s < 4; ++s) {
#pragma unroll
        for (int ks = 0; ks < 2; ++ks) {
            short8 af[4], bf[4];
            const int g0 = s * 8 + ks * 4 + quad;
#pragma unroll
            for (int tr = 0; tr < 4; ++tr) {
                int r = tr * 16 + c15;
                af[tr] = *(const short8*)&Ts[r * 256 + ((g0 ^ (r & 31)) * 8)];
            }
#pragma unroll
            for (int tc = 0; tc < 4; ++tc) {
                int n = w * 64 + tc * 16 + c15;
                bf[tc] = *(const short8*)&Bs2[0][n * 64 + (((ks * 4 + quad) ^ (n & 7)) * 8)];
            }
#pragma unroll
            for (int tr = 0; tr < 4; ++tr)
#pragma unroll
                for (int tc = 0; tc < 4; ++tc)
                    acc[tr][tc] = __builtin_amdgcn_mfma_f32_16x16x32_bf16(
                        af[tr], bf[tc], acc[tr][tc], 0, 0, 0);
        }
        if (s < 3) {
            __syncthreads();                       // all waves done with Bs2[0]
            stageB(0, W2c, 256, (s + 1) * 64);     // restage (L2-hot)
            __syncthreads();                       // drain + publish
        }
    }

    // ---- Phase 3: relu(acc+b2) dot w3 ----
    float b2v[4], w3v[4];
#pragma unroll
    for (int tc = 0; tc < 4; ++tc) {
        int col = w * 64 + tc * 16 + c15;
        b2v[tc] = b2[c * 256 + col];
        w3v[tc] = w3[c * 256 + col];
    }
    __syncthreads();                 // As2 region retired before red alias use
#pragma unroll
    for (int tr = 0; tr < 4; ++tr)
#pragma unroll
        for (int rg = 0; rg < 4; ++rg) {
            float p = 0.f;
#pragma unroll
            for (int tc = 0; tc < 4; ++tc)
                p += fmaxf(acc[tr][tc][rg] + b2v[tc], 0.f) * w3v[tc];
            p += __shfl_xor(p, 1);
            p += __shfl_xor(p, 2);
            p += __shfl_xor(p, 4);
            p += __shfl_xor(p, 8);
            if (c15 == 0) red[tr * 16 + quad * 4 + rg][w] = p;
        }
    __syncthreads();
    if (t < 64) {
        int grow = rowbase + t;
        if (grow < N) {
            float s = red[t][0] + red[t][1] + red[t][2] + red[t][3] + b3[c];
            out[(size_t)grow * NCH + c] = fmaxf(s, 0.f);
        }
    }
}

// ---------------------------------------------------------------------------
// Launch
// ---------------------------------------------------------------------------
extern "C" void kernel_launch(void* const* d_in, const int* in_sizes, int n_in,
                              void* d_out, int out_size, void* d_ws, size_t ws_size,
                              hipStream_t stream) {
    const float* x        = (const float*)d_in[0];
    const int*   eidx     = (const int*)d_in[1];
    const float* convW    = (const float*)d_in[2];
    const float* convB    = (const float*)d_in[3];
    const float* chanW1   = (const float*)d_in[4];
    const float* chanB1   = (const float*)d_in[5];
    const float* chanW2   = (const float*)d_in[6];
    const float* chanB2   = (const float*)d_in[7];
    const float* chanW3   = (const float*)d_in[8];
    const float* chanB3   = (const float*)d_in[9];
    float* out = (float*)d_out;

    const int N = in_sizes[0] / D;      // 100000
    const int E = in_sizes[1] / 2;      // 1600000
    const int* srcp = eidx;
    const int* dstp = eidx + E;
    const int nb = (N + 255) / 256;     // 391

    char* w = (char*)d_ws;
    auto take = [&](size_t bytes) {
        char* p = w;
        w += (bytes + 255) & ~(size_t)255;
        return p;
    };
    ushort* xb     = (ushort*)take((size_t)N * D * 2);
    ushort* h0     = (ushort*)take((size_t)N * D * 2);
    ushort* h1     = (ushort*)take((size_t)N * D * 2);
    ushort* h2     = (ushort*)take((size_t)N * D * 2);
    int*    deg    = (int*)take((size_t)N * 4);
    int*    offs   = (int*)take((size_t)(N + 1) * 4);
    int*    cursor = (int*)take((size_t)N * 4);
    int*    bsum   = (int*)take((size_t)nb * 4);
    int*    boff   = (int*)take((size_t)nb * 4);
    ushort* Wt1b   = (ushort*)take((size_t)NCH * 256 * 512 * 2);
    ushort* Wt2b   = (ushort*)take((size_t)NCH * 256 * 256 * 2);
    ushort* WtC    = (ushort*)take((size_t)NLAYER * 3 * D * D * 2);

    size_t used = (size_t)(w - (char*)d_ws);
    if (used > ws_size) return;
    size_t rem = ws_size - used;
    size_t need_gin = (((size_t)E * 4 + 255) & ~(size_t)255) + (size_t)N * D * 2;
    if (rem < need_gin) return;

    int*    csr = (int*)w;
    ushort* a   = (ushort*)(w + (((size_t)E * 4 + 255) & ~(size_t)255));

    // --- CSR build (XCD-partitioned hist + parallel scan + partitioned fill) ---
    hipMemsetAsync(deg, 0, (size_t)N * 4, stream);
    {
        int nchunks = (E + FILL_CHUNK - 1) / FILL_CHUNK;
        int nPer = (N + 7) / 8;
        hist_part_kernel<<<nchunks * 8, 256, 0, stream>>>(dstp, deg, E, nPer, N);
        blocksum_kernel<<<nb, 256, 0, stream>>>(deg, bsum, N);
        scanblk_kernel<<<1, 512, 0, stream>>>(bsum, boff, nb, offs, N, E);
        blockscan_kernel<<<nb, 256, 0, stream>>>(deg, boff, offs, cursor, N);
        fill_part_kernel<<<nchunks * 8, 256, 0, stream>>>(
            srcp, dstp, cursor, csr, E, nPer, N);
    }

    // --- converts (independent) ---
    cvtx_kernel<<<(N * 16 + 255) / 256, 256, 0, stream>>>(x, xb, N * 16);
    cvtW_kernel<<<dim3(512 / 32, 256 / 32, NCH), 256, 0, stream>>>(chanW1, Wt1b, 512, 256);
    cvtW_kernel<<<dim3(256 / 32, 256 / 32, NCH), 256, 0, stream>>>(chanW2, Wt2b, 256, 256);
    cvtW_kernel<<<dim3(D / 32, D / 32, NLAYER * 3), 256, 0, stream>>>(convW, WtC, D, D);

    const int rowtiles = (N + 127) / 128;
    const int aggblocks = (N * 16 + 255) / 256;      // 16 nodes per 256-thread block

    // --- GIN layers: agg + fused 3-linear MLP per layer ---
    ushort* hbuf[NLAYER] = {h0, h1, h2};
    const ushort* prev = xb;
    for (int l = 0; l < NLAYER; ++l) {
        agg_bf16<<<aggblocks, 256, 0, stream>>>(prev, offs, csr, a, N);
        gin_mlp_mfma<<<rowtiles, 256, 0, stream>>>(
            a, WtC + (size_t)l * 3 * D * D, convB + (size_t)l * 3 * D, hbuf[l], N);
        prev = hbuf[l];
    }

    // --- channel MLPs: fused, 64-row tiles, XCD-aware swizzled grid ---
    {
        const int T = (N + 63) / 64;          // 1563 row tiles
        const int chunkT = (T + 7) / 8;       // row tiles per XCD class
        const int grid = 8 * chunkT * NCH;
        chan_fused_mfma<<<grid, 256, 0, stream>>>(
            xb, h0, h1, h2,
            Wt1b, chanB1, Wt2b, chanB2, chanW3, chanB3,
            out, N, T, chunkT);
    }
}